// Round 1
// 443.582 us; speedup vs baseline: 1.9857x; 1.9857x over previous
//
#include <hip/hip_runtime.h>
#include <hip/hip_bf16.h>

typedef unsigned short u16;
using bf16_t = __hip_bfloat16;
typedef short short8 __attribute__((ext_vector_type(8)));
typedef float f32x4 __attribute__((ext_vector_type(4)));

__device__ __forceinline__ float b2f(u16 u) {
    return __uint_as_float((unsigned int)u << 16);
}
__device__ __forceinline__ u16 f2b(float f) {
    bf16_t h = __float2bfloat16(f);
    union { bf16_t h; u16 u; } cv; cv.h = h; return cv.u;
}
__device__ __forceinline__ float ldv(const void* p, size_t i, int f32) {
    return f32 ? ((const float*)p)[i] : b2f(((const u16*)p)[i]);
}

// ---------------------------------------------------------------------------
// Input-dtype detector (flag=1 -> fp32 inputs & fp32 output).
// ---------------------------------------------------------------------------
__global__ void detect_kernel(const void* __restrict__ x, int* __restrict__ flag)
{
    const int t = threadIdx.x;
    const u16 h = ((const u16*)x)[2 * t];
    const int e = (h >> 7) & 0xFF;
    const int plaus = (e >= 112 && e <= 133) ? 1 : 0;
    const unsigned long long m = __ballot(plaus);
    if (t == 0) flag[0] = (__popcll(m) < 32) ? 1 : 0;
}

// pe -> peb (bf16 always).
__global__ __launch_bounds__(256)
void pecvt_kernel(const void* __restrict__ pe, u16* __restrict__ peb,
                  const int* __restrict__ flagp)
{
    const size_t i = ((size_t)blockIdx.x * 256 + threadIdx.x) * 4;
    if (*flagp) {
        const float4 f = *reinterpret_cast<const float4*>((const float*)pe + i);
        ushort4 o; o.x = f2b(f.x); o.y = f2b(f.y); o.z = f2b(f.z); o.w = f2b(f.w);
        *reinterpret_cast<ushort4*>(peb + i) = o;
    } else {
        *reinterpret_cast<ushort4*>(peb + i) =
            *reinterpret_cast<const ushort4*>((const u16*)pe + i);
    }
}

// W[K x N] -> WT[N x K(=256)] bf16, LDS-tiled transpose.
__global__ __launch_bounds__(256)
void wtrans_kernel(const void* __restrict__ W, u16* __restrict__ WT, int N,
                   const int* __restrict__ flagp)
{
    const int f32 = *flagp;
    __shared__ float tile[32][33];
    const int tx = threadIdx.x & 31, ty = threadIdx.x >> 5;   // ty 0..7
    const int bx = blockIdx.x % (N >> 5);   // n tile
    const int by = blockIdx.x / (N >> 5);   // k tile
    #pragma unroll
    for (int r = 0; r < 4; ++r) {
        const int k = by * 32 + ty + r * 8;
        const int n = bx * 32 + tx;
        tile[ty + r * 8][tx] = ldv(W, (size_t)k * N + n, f32);
    }
    __syncthreads();
    #pragma unroll
    for (int r = 0; r < 4; ++r) {
        const int n2 = bx * 32 + ty + r * 8;
        const int k2 = by * 32 + tx;
        WT[(size_t)n2 * 256 + k2] = f2b(tile[tx][ty + r * 8]);
    }
}

// ---------------------------------------------------------------------------
// MFMA GEMM (verified): O[rows x 256] = A[rows x 256] @ B. 128x128 tile,
// BK=64, 4 waves (2x2), each wave 4x4 grid of 16x16x32 bf16 MFMA tiles.
// MODE 0: O0(bf16) = A@B       (A = external x, fp32 or bf16)
// MODE 2: out = A@B + bias; fp32 or bf16 store per flag. (A = internal bf16)
// ---------------------------------------------------------------------------
template<int MODE>
__global__ __launch_bounds__(256)
void gemm_mfma(const void* __restrict__ Aany, const u16* __restrict__ Abf,
               const u16* __restrict__ BT,
               u16* __restrict__ O0, u16* __restrict__ O1,
               const void* __restrict__ extra, const u16* __restrict__ peb,
               int row_base, const int* __restrict__ flagp)
{
    const int f32 = *flagp;

    __shared__ u16 As[128 * 72];   // [m][k], stride 72 (pad 8: 16B-aligned rows)
    __shared__ u16 Bs[128 * 72];   // [n][k]

    const int tid  = threadIdx.x;
    const int row0 = blockIdx.y * 128;
    const int col0 = blockIdx.x * 128;

    const int lane = tid & 63;
    const int wv   = tid >> 6;
    const int wm   = (wv & 1) * 64;
    const int wn   = (wv >> 1) * 64;
    const int l15  = lane & 15;
    const int lq   = lane >> 4;

    const int sr = tid >> 1;              // staging row 0..127
    const int sk = (tid & 1) * 32;        // staging k-half

    f32x4 acc[4][4] = {};

    for (int k0 = 0; k0 < 256; k0 += 64) {
        u16* al = &As[sr * 72 + sk];
        u16* bl = &Bs[sr * 72 + sk];
        const size_t arow = (size_t)(row_base + row0 + sr) * 256 + k0 + sk;
        if (MODE != 2 && f32) {
            const float* ag = (const float*)Aany + arow;
            #pragma unroll
            for (int j = 0; j < 4; ++j) {
                const float4 f0 = *reinterpret_cast<const float4*>(ag + j * 8);
                const float4 f1 = *reinterpret_cast<const float4*>(ag + j * 8 + 4);
                ushort4 p0, p1;
                p0.x = f2b(f0.x); p0.y = f2b(f0.y); p0.z = f2b(f0.z); p0.w = f2b(f0.w);
                p1.x = f2b(f1.x); p1.y = f2b(f1.y); p1.z = f2b(f1.z); p1.w = f2b(f1.w);
                *reinterpret_cast<ushort4*>(al + j * 8)     = p0;
                *reinterpret_cast<ushort4*>(al + j * 8 + 4) = p1;
            }
        } else {
            const u16* ag = ((MODE == 2) ? Abf : (const u16*)Aany) + arow;
            #pragma unroll
            for (int j = 0; j < 4; ++j)
                *reinterpret_cast<uint4*>(al + j * 8) =
                    *reinterpret_cast<const uint4*>(ag + j * 8);
        }
        const u16* bg = BT + (size_t)(col0 + sr) * 256 + k0 + sk;
        #pragma unroll
        for (int j = 0; j < 4; ++j)
            *reinterpret_cast<uint4*>(bl + j * 8) =
                *reinterpret_cast<const uint4*>(bg + j * 8);
        __syncthreads();
        #pragma unroll
        for (int ks = 0; ks < 64; ks += 32) {
            short8 av[4], bvv[4];
            #pragma unroll
            for (int i = 0; i < 4; ++i)
                av[i] = *reinterpret_cast<const short8*>(
                    &As[(wm + i * 16 + l15) * 72 + ks + lq * 8]);
            #pragma unroll
            for (int j = 0; j < 4; ++j)
                bvv[j] = *reinterpret_cast<const short8*>(
                    &Bs[(wn + j * 16 + l15) * 72 + ks + lq * 8]);
            #pragma unroll
            for (int i = 0; i < 4; ++i)
                #pragma unroll
                for (int j = 0; j < 4; ++j)
                    acc[i][j] = __builtin_amdgcn_mfma_f32_16x16x32_bf16(
                        av[i], bvv[j], acc[i][j], 0, 0, 0);
        }
        __syncthreads();
    }

    // Epilogue. C/D layout: row=(lane>>4)*4+reg, col=lane&15 (m89-verified).
    #pragma unroll
    for (int i = 0; i < 4; ++i) {
        #pragma unroll
        for (int j = 0; j < 4; ++j) {
            const int gcol = col0 + wn + j * 16 + l15;
            #pragma unroll
            for (int rg = 0; rg < 4; ++rg) {
                const int lrow = row0 + wm + i * 16 + lq * 4 + rg;  // local row
                const float a = acc[i][j][rg];
                if (MODE == 0) {
                    O0[(size_t)lrow * 256 + gcol] = f2b(a);
                } else {
                    const float o = a + ldv(extra, gcol, f32);
                    if (f32) ((float*)O0)[(size_t)lrow * 256 + gcol] = o;
                    else     O0[(size_t)lrow * 256 + gcol] = f2b(o);
                }
            }
        }
    }
}

// ---------------------------------------------------------------------------
// Fused k-path: k = x @ Wkv[:, :256] + pe  -> focus -> kvsum/ksum atomics.
// k is never written to global memory.
// Block: 64 rows x 256 cols, 256 threads = 4 waves (1x4 in N).
// Phase 1: GEMM (same fragment layouts as gemm_mfma).
// Phase 2: +peb, focus (shfl over 16-lane col groups + LDS cross-wave),
//          store bf16 k to LDS (aliases dead GEMM staging), ksum atomics.
// Phase 3: kvsum = K^T @ V per head via MFMA (K-dim = 64 block rows),
//          A gathered from LDS k, B gathered from global v, f32 atomics.
// ---------------------------------------------------------------------------
__global__ __launch_bounds__(256, 3)
void fusedk_kernel(const void* __restrict__ x, const u16* __restrict__ WkvT,
                   const u16* __restrict__ peb, const u16* __restrict__ v,
                   const void* __restrict__ sp,
                   float* __restrict__ kvsm, float* __restrict__ ksm,
                   const int* __restrict__ flagp)
{
    const int f32 = *flagp;
    __shared__ u16 smem[23040];          // As 64x72 | Bs 256x72 ; then Ks 64x264
    __shared__ float red2[4][64];
    __shared__ float red6[4][64];
    __shared__ float ratio_s[64];
    __shared__ float sscr[256];
    u16* As = smem;                      // [64][72]
    u16* Bs = smem + 64 * 72;            // [256][72]
    u16* Ks = smem;                      // [64][264] bf16 focused k (aliased)

    const int tid  = threadIdx.x;
    const int lane = tid & 63;
    const int wv   = tid >> 6;           // 0..3
    const int l15  = lane & 15;
    const int lq   = lane >> 4;
    const int wn   = wv * 64;

    const int row0 = blockIdx.x * 64;    // global row (b*4096 + n)
    const int b    = row0 >> 12;
    const int nb   = row0 & 4095;

    {
        const float p = ldv(sp, tid, f32);
        const float s = (p > 20.f) ? p : log1pf(expf(p));
        sscr[tid] = 1.0f / s;
    }

    f32x4 acc[4][4] = {};

    const int ar = tid >> 2, ak = (tid & 3) * 16;
    for (int k0 = 0; k0 < 256; k0 += 64) {
        // A: row ar (0..63), 16 u16 at k0+ak.
        u16* al = &As[ar * 72 + ak];
        const size_t arow = (size_t)(row0 + ar) * 256 + k0 + ak;
        if (f32) {
            const float* ag = (const float*)x + arow;
            #pragma unroll
            for (int j = 0; j < 2; ++j) {
                const float4 f0 = *reinterpret_cast<const float4*>(ag + j * 8);
                const float4 f1 = *reinterpret_cast<const float4*>(ag + j * 8 + 4);
                ushort4 p0, p1;
                p0.x = f2b(f0.x); p0.y = f2b(f0.y); p0.z = f2b(f0.z); p0.w = f2b(f0.w);
                p1.x = f2b(f1.x); p1.y = f2b(f1.y); p1.z = f2b(f1.z); p1.w = f2b(f1.w);
                *reinterpret_cast<ushort4*>(al + j * 8)     = p0;
                *reinterpret_cast<ushort4*>(al + j * 8 + 4) = p1;
            }
        } else {
            const u16* ag = (const u16*)x + arow;
            #pragma unroll
            for (int j = 0; j < 2; ++j)
                *reinterpret_cast<uint4*>(al + j * 8) =
                    *reinterpret_cast<const uint4*>(ag + j * 8);
        }
        // B: row tid (0..255) of WkvT (k part), 64 u16 at k0.
        {
            u16* bl = &Bs[tid * 72];
            const u16* bg = WkvT + (size_t)tid * 256 + k0;
            #pragma unroll
            for (int j = 0; j < 8; ++j)
                *reinterpret_cast<uint4*>(bl + j * 8) =
                    *reinterpret_cast<const uint4*>(bg + j * 8);
        }
        __syncthreads();
        #pragma unroll
        for (int ks = 0; ks < 64; ks += 32) {
            short8 av[4], bvv[4];
            #pragma unroll
            for (int i = 0; i < 4; ++i)
                av[i] = *reinterpret_cast<const short8*>(
                    &As[(i * 16 + l15) * 72 + ks + lq * 8]);
            #pragma unroll
            for (int j = 0; j < 4; ++j)
                bvv[j] = *reinterpret_cast<const short8*>(
                    &Bs[(wn + j * 16 + l15) * 72 + ks + lq * 8]);
            #pragma unroll
            for (int i = 0; i < 4; ++i)
                #pragma unroll
                for (int j = 0; j < 4; ++j)
                    acc[i][j] = __builtin_amdgcn_mfma_f32_16x16x32_bf16(
                        av[i], bvv[j], acc[i][j], 0, 0, 0);
        }
        __syncthreads();
    }

    // ---- Phase 2a: +peb, normalize, per-row partial s2/s6 + reduce. -------
    #pragma unroll
    for (int i = 0; i < 4; ++i) {
        #pragma unroll
        for (int rg = 0; rg < 4; ++rg) {
            const int lrow = i * 16 + lq * 4 + rg;
            float s2 = 0.f, s6 = 0.f;
            #pragma unroll
            for (int j = 0; j < 4; ++j) {
                const int col = wn + j * 16 + l15;
                const float t = acc[i][j][rg] +
                    b2f(peb[(size_t)(nb + lrow) * 256 + col]);
                const float xv = (fmaxf(t, 0.f) + 1e-6f) * sscr[col];
                acc[i][j][rg] = xv;
                const float x2 = xv * xv;
                s2 += x2;
                s6 += x2 * x2 * x2;
            }
            #pragma unroll
            for (int off = 1; off < 16; off <<= 1) {
                s2 += __shfl_xor(s2, off);
                s6 += __shfl_xor(s6, off);
            }
            if (l15 == 0) { red2[wv][lrow] = s2; red6[wv][lrow] = s6; }
        }
    }
    __syncthreads();
    if (tid < 64) {
        const float s2t = red2[0][tid] + red2[1][tid] + red2[2][tid] + red2[3][tid];
        const float s6t = red6[0][tid] + red6[1][tid] + red6[2][tid] + red6[3][tid];
        ratio_s[tid] = sqrtf(s2t / s6t);
    }
    __syncthreads();

    // ---- Phase 2b: finalize k, stash bf16 to LDS, ksum column partials. ---
    float kscol[4] = {0.f, 0.f, 0.f, 0.f};
    #pragma unroll
    for (int i = 0; i < 4; ++i) {
        #pragma unroll
        for (int rg = 0; rg < 4; ++rg) {
            const int lrow = i * 16 + lq * 4 + rg;
            const float rt = ratio_s[lrow];
            #pragma unroll
            for (int j = 0; j < 4; ++j) {
                const float xv = acc[i][j][rg];
                const float kf = xv * xv * xv * rt;
                Ks[lrow * 264 + wn + j * 16 + l15] = f2b(kf);
                kscol[j] += kf;
            }
        }
    }
    #pragma unroll
    for (int j = 0; j < 4; ++j) {
        float kp = kscol[j];
        kp += __shfl_xor(kp, 16);
        kp += __shfl_xor(kp, 32);
        if (lane < 16)
            atomicAdd(&ksm[(size_t)b * 256 + wn + j * 16 + lane], kp);
    }
    __syncthreads();

    // ---- Phase 3: kvsum per head via MFMA: C[d][e] = sum_r k[r][d] v[r][e].
    // Wave wv handles heads 2*wv, 2*wv+1 (cols [wn, wn+64) == what it wrote).
    #pragma unroll
    for (int hh = 0; hh < 2; ++hh) {
        const int h  = wv * 2 + hh;
        const int cb = h * 32;
        f32x4 c00 = {}, c01 = {}, c10 = {}, c11 = {};
        #pragma unroll
        for (int kk = 0; kk < 64; kk += 32) {
            short8 a0, a1, b0, b1;
            #pragma unroll
            for (int j = 0; j < 8; ++j) {
                const int r = kk + lq * 8 + j;
                a0[j] = (short)Ks[r * 264 + cb + l15];
                a1[j] = (short)Ks[r * 264 + cb + 16 + l15];
                const size_t vrow = (size_t)(row0 + r) * 256 + cb;
                b0[j] = (short)v[vrow + l15];
                b1[j] = (short)v[vrow + 16 + l15];
            }
            c00 = __builtin_amdgcn_mfma_f32_16x16x32_bf16(a0, b0, c00, 0, 0, 0);
            c01 = __builtin_amdgcn_mfma_f32_16x16x32_bf16(a0, b1, c01, 0, 0, 0);
            c10 = __builtin_amdgcn_mfma_f32_16x16x32_bf16(a1, b0, c10, 0, 0, 0);
            c11 = __builtin_amdgcn_mfma_f32_16x16x32_bf16(a1, b1, c11, 0, 0, 0);
        }
        float* base = kvsm + (size_t)(b * 8 + h) * 1024;
        #pragma unroll
        for (int rg = 0; rg < 4; ++rg) {
            const int d0 = lq * 4 + rg;
            atomicAdd(&base[(size_t)d0 * 32 + l15],             c00[rg]);
            atomicAdd(&base[(size_t)d0 * 32 + 16 + l15],        c01[rg]);
            atomicAdd(&base[(size_t)(d0 + 16) * 32 + l15],      c10[rg]);
            atomicAdd(&base[(size_t)(d0 + 16) * 32 + 16 + l15], c11[rg]);
        }
    }
}

// ---------------------------------------------------------------------------
// Focus: t=(relu(t)+eps)/softplus(p); t := t^3 * ||t||/||t^3||. In-place bf16.
// (Used for q only; the k path is fused into fusedk_kernel.)
// ---------------------------------------------------------------------------
__global__ __launch_bounds__(256)
void focus_kernel(u16* __restrict__ buf, const void* __restrict__ scale_param,
                  const int* __restrict__ flagp)
{
    const int f32 = *flagp;
    __shared__ float ssc[256];
    const int tid = threadIdx.x;
    {
        const float p = ldv(scale_param, tid, f32);
        ssc[tid] = (p > 20.f) ? p : log1pf(expf(p));
    }
    __syncthreads();
    const int lane = tid & 63;
    const int wv   = tid >> 6;
    const size_t row = (size_t)blockIdx.x * 4 + wv;
    u16* t = buf + row * 256;
    float tv[4]; float s2 = 0.f, s6 = 0.f;
    #pragma unroll
    for (int i = 0; i < 4; ++i) {
        const int c = lane + i * 64;
        float x = b2f(t[c]);
        x = fmaxf(x, 0.f) + 1e-6f;
        x = x / ssc[c];
        tv[i] = x;
        const float x2 = x * x;
        s2 += x2;
        const float x3 = x2 * x;
        s6 += x3 * x3;
    }
    #pragma unroll
    for (int off = 32; off > 0; off >>= 1) {
        s2 += __shfl_xor(s2, off);
        s6 += __shfl_xor(s6, off);
    }
    const float ratio = sqrtf(s2 / s6);
    #pragma unroll
    for (int i = 0; i < 4; ++i) {
        const int c = lane + i * 64;
        const float x = tv[i];
        t[c] = f2b(x * x * x * ratio);
    }
}

// ---------------------------------------------------------------------------
// attn IN-PLACE on qy.
// ---------------------------------------------------------------------------
__global__ __launch_bounds__(256)
void attn_kernel(u16* qy, const float* __restrict__ kvsum,
                 const float* __restrict__ ksum)
{
    __shared__ float kvs[8][32][32];
    __shared__ float km[8][32];
    __shared__ float qs[16][256];
    const int tid = threadIdx.x;
    const int b   = blockIdx.x >> 8;
    const int n0  = (blockIdx.x & 255) * 16;
    const float inv_n = 1.0f / 4096.0f;
    for (int i = tid; i < 8 * 32 * 32; i += 256)
        (&kvs[0][0][0])[i] = kvsum[(size_t)b * 8192 + i] * inv_n;
    (&km[0][0])[tid] = ksum[(size_t)b * 256 + tid] * inv_n;
    u16* qb = qy + ((size_t)b * 4096 + n0) * 256;
    #pragma unroll
    for (int t = 0; t < 16; ++t)
        qs[t][tid] = b2f(qb[(size_t)t * 256 + tid]);
    __syncthreads();
    const int h = tid >> 5, e = tid & 31;
    for (int t = 0; t < 16; ++t) {
        float acc = 0.f, zd = 0.f;
        #pragma unroll
        for (int d = 0; d < 32; ++d) {
            const float qv = qs[t][h * 32 + d];
            acc = fmaf(qv, kvs[h][d][e], acc);
            zd  = fmaf(qv, km[h][d], zd);
        }
        qb[(size_t)t * 256 + tid] = f2b(acc / (zd + 1e-6f));
    }
}

// ---------------------------------------------------------------------------
// Depthwise 5x5 conv v2: LDS-staged 12x12x256 halo tile (vectorized uint4
// staging), thread=channel, register-resident sliding 5x12 window (each LDS
// element read exactly once), 8x8 outputs/thread, += into y with bias.
// __launch_bounds__(256,2): allow ~110 VGPRs (previous version was squeezed
// to 48 VGPRs -> window spilled -> L1-latency-bound at 26% VALU).
// ---------------------------------------------------------------------------
__global__ __launch_bounds__(256, 2)
void conv_add_kernel(const u16* __restrict__ v, const void* __restrict__ w,
                     const void* __restrict__ bias, u16* __restrict__ y,
                     const int* __restrict__ flagp)
{
    const int f32 = *flagp;
    __shared__ u16 vt[144 * 256];   // [py*12+px][ch], 73728 B
    __shared__ float wl[800];
    __shared__ float bl[32];
    const int tid = threadIdx.x;
    for (int i = tid; i < 800; i += 256) wl[i] = ldv(w, i, f32);
    if (tid < 32) bl[tid] = ldv(bias, tid, f32);

    const int bb = blockIdx.x >> 6;
    const int ty = (blockIdx.x >> 3) & 7;
    const int tx = blockIdx.x & 7;
    const int y0 = ty * 8, x0 = tx * 8;
    const u16* vb = v + (size_t)bb * 4096 * 256;

    #pragma unroll
    for (int it = 0; it < 18; ++it) {
        const int idx = it * 256 + tid;       // 0..4607
        const int px  = idx >> 5;             // 0..143
        const int c8  = (idx & 31) * 8;
        const int py  = px / 12, pxx = px - py * 12;
        const int yy = y0 + py - 2, xx = x0 + pxx - 2;
        uint4 val = {0u, 0u, 0u, 0u};
        if (yy >= 0 && yy < 64 && xx >= 0 && xx < 64)
            val = *reinterpret_cast<const uint4*>(
                vb + (size_t)((yy << 6) + xx) * 256 + c8);
        *reinterpret_cast<uint4*>(&vt[px * 256 + c8]) = val;
    }
    __syncthreads();

    const int c  = tid;            // channel
    const int dc = c & 31;
    float wreg[25];
    #pragma unroll
    for (int i = 0; i < 25; ++i) wreg[i] = wl[dc * 25 + i];
    const float bv = bl[dc];

    float win[5][12];
    #pragma unroll
    for (int r = 0; r < 5; ++r)
        #pragma unroll
        for (int cc = 0; cc < 12; ++cc)
            win[r][cc] = b2f(vt[(r * 12 + cc) * 256 + c]);

    u16* yb = y + ((size_t)bb * 4096 + (size_t)y0 * 64 + x0) * 256 + c;
    #pragma unroll
    for (int oy = 0; oy < 8; ++oy) {
        if (oy) {
            #pragma unroll
            for (int r = 0; r < 4; ++r)
                #pragma unroll
                for (int cc = 0; cc < 12; ++cc) win[r][cc] = win[r + 1][cc];
            #pragma unroll
            for (int cc = 0; cc < 12; ++cc)
                win[4][cc] = b2f(vt[((oy + 4) * 12 + cc) * 256 + c]);
        }
        #pragma unroll
        for (int ox = 0; ox < 8; ++ox) {
            float s = 0.f;
            #pragma unroll
            for (int ky = 0; ky < 5; ++ky)
                #pragma unroll
                for (int kx = 0; kx < 5; ++kx)
                    s = fmaf(win[ky][ox + kx], wreg[ky * 5 + kx], s);
            u16* yp = yb + (size_t)(oy * 64 + ox) * 256;
            *yp = f2b(b2f(*yp) + s + bv);
        }
    }
}

// ---------------------------------------------------------------------------
extern "C" void kernel_launch(void* const* d_in, const int* in_sizes, int n_in,
                              void* d_out, int out_size, void* d_ws, size_t ws_size,
                              hipStream_t stream)
{
    (void)in_sizes; (void)n_in; (void)out_size; (void)ws_size;
    const void* x   = d_in[0];
    const void* Wq  = d_in[1];
    const void* Wkv = d_in[2];
    const void* Wp  = d_in[3];
    const void* bp  = d_in[4];
    const void* sp  = d_in[5];
    const void* pe  = d_in[6];
    const void* dw  = d_in[7];
    const void* db  = d_in[8];

    // ws layout (~36 MB):
    // [flag 64B][kvsm 512K][ksm 16K][WqT 128K][WkvT 256K][WpT 128K][peb 2M][qy 33.5M]
    int*   flag = (int*)d_ws;
    float* kvsm = (float*)((char*)d_ws + 64);
    float* ksm  = kvsm + 131072;
    u16*   WqT  = (u16*)(ksm + 4096);
    u16*   WkvT = WqT + 65536;
    u16*   WpT  = WkvT + 131072;
    u16*   peb  = WpT + 65536;
    u16*   qy   = peb + 1048576;
    // v (bf16, 33.5 MB) parked at the START of d_out (d_out is 64 MB fp32 or
    // 33.5 MB bf16 — fits either way); dead before the final GEMM overwrites.
    u16*   v    = (u16*)d_out;

    hipMemsetAsync(kvsm, 0, (131072 + 4096) * sizeof(float), stream);
    detect_kernel<<<1, 64, 0, stream>>>(x, flag);
    pecvt_kernel<<<1024, 256, 0, stream>>>(pe, peb, flag);
    wtrans_kernel<<<64, 256, 0, stream>>>(Wq, WqT, 256, flag);
    wtrans_kernel<<<128, 256, 0, stream>>>(Wkv, WkvT, 512, flag);
    wtrans_kernel<<<64, 256, 0, stream>>>(Wp, WpT, 256, flag);

    // q = x @ Wq (65536 rows)
    hipLaunchKernelGGL((gemm_mfma<0>), dim3(2, 512), dim3(256), 0, stream,
                       x, (const u16*)nullptr, WqT, qy, (u16*)nullptr,
                       (const void*)nullptr, (const u16*)nullptr, 0, flag);
    focus_kernel<<<16384, 256, 0, stream>>>(qy, sp, flag);
    // v = x @ Wkv[:, 256:]  (WkvT rows 256..511)
    hipLaunchKernelGGL((gemm_mfma<0>), dim3(2, 512), dim3(256), 0, stream,
                       x, (const u16*)nullptr, WkvT + (size_t)256 * 256, v,
                       (u16*)nullptr, (const void*)nullptr, (const u16*)nullptr,
                       0, flag);
    // fused k path: gemm + pe + focus + kvsum/ksum (k never materialized)
    fusedk_kernel<<<1024, 256, 0, stream>>>(x, WkvT, peb, v, sp, kvsm, ksm, flag);

    attn_kernel<<<4096, 256, 0, stream>>>(qy, kvsm, ksm);
    conv_add_kernel<<<1024, 256, 0, stream>>>(v, dw, db, qy, flag);
    hipLaunchKernelGGL((gemm_mfma<2>), dim3(2, 512), dim3(256), 0, stream,
                       (const void*)nullptr, qy, WpT, (u16*)d_out, (u16*)nullptr,
                       bp, (const u16*)nullptr, 0, flag);
}

// Round 2
// 386.224 us; speedup vs baseline: 2.2806x; 1.1485x over previous
//
#include <hip/hip_runtime.h>
#include <hip/hip_bf16.h>

typedef unsigned short u16;
using bf16_t = __hip_bfloat16;
typedef short short8 __attribute__((ext_vector_type(8)));
typedef float f32x4 __attribute__((ext_vector_type(4)));

__device__ __forceinline__ float b2f(u16 u) {
    return __uint_as_float((unsigned int)u << 16);
}
__device__ __forceinline__ u16 f2b(float f) {
    bf16_t h = __float2bfloat16(f);
    union { bf16_t h; u16 u; } cv; cv.h = h; return cv.u;
}
__device__ __forceinline__ float ldv(const void* p, size_t i, int f32) {
    return f32 ? ((const float*)p)[i] : b2f(((const u16*)p)[i]);
}

// ---------------------------------------------------------------------------
// Input-dtype detector (flag=1 -> fp32 inputs & fp32 output).
// ---------------------------------------------------------------------------
__global__ void detect_kernel(const void* __restrict__ x, int* __restrict__ flag)
{
    const int t = threadIdx.x;
    const u16 h = ((const u16*)x)[2 * t];
    const int e = (h >> 7) & 0xFF;
    const int plaus = (e >= 112 && e <= 133) ? 1 : 0;
    const unsigned long long m = __ballot(plaus);
    if (t == 0) flag[0] = (__popcll(m) < 32) ? 1 : 0;
}

// pe -> peb (bf16 always).
__global__ __launch_bounds__(256)
void pecvt_kernel(const void* __restrict__ pe, u16* __restrict__ peb,
                  const int* __restrict__ flagp)
{
    const size_t i = ((size_t)blockIdx.x * 256 + threadIdx.x) * 4;
    if (*flagp) {
        const float4 f = *reinterpret_cast<const float4*>((const float*)pe + i);
        ushort4 o; o.x = f2b(f.x); o.y = f2b(f.y); o.z = f2b(f.z); o.w = f2b(f.w);
        *reinterpret_cast<ushort4*>(peb + i) = o;
    } else {
        *reinterpret_cast<ushort4*>(peb + i) =
            *reinterpret_cast<const ushort4*>((const u16*)pe + i);
    }
}

// W[K x N] -> WT[N x K(=256)] bf16, LDS-tiled transpose.
__global__ __launch_bounds__(256)
void wtrans_kernel(const void* __restrict__ W, u16* __restrict__ WT, int N,
                   const int* __restrict__ flagp)
{
    const int f32 = *flagp;
    __shared__ float tile[32][33];
    const int tx = threadIdx.x & 31, ty = threadIdx.x >> 5;   // ty 0..7
    const int bx = blockIdx.x % (N >> 5);   // n tile
    const int by = blockIdx.x / (N >> 5);   // k tile
    #pragma unroll
    for (int r = 0; r < 4; ++r) {
        const int k = by * 32 + ty + r * 8;
        const int n = bx * 32 + tx;
        tile[ty + r * 8][tx] = ldv(W, (size_t)k * N + n, f32);
    }
    __syncthreads();
    #pragma unroll
    for (int r = 0; r < 4; ++r) {
        const int n2 = bx * 32 + ty + r * 8;
        const int k2 = by * 32 + tx;
        WT[(size_t)n2 * 256 + k2] = f2b(tile[tx][ty + r * 8]);
    }
}

// ---------------------------------------------------------------------------
// MFMA GEMM, BN=256 (single col tile): O[rows x 256] = A[rows x 256] @ B.
// 128x256 block tile, BK=64, 4 waves as 2(m)x2(n); wave tile 64x128 =
// acc[4][8] of 16x16 frags. Reads A (x, fp32 64 MB) exactly ONCE total.
// MODE 0: O0(bf16) = A@B                      (A external, v-gemm)
// MODE 2: out = A@B + bias; fp32/bf16 store   (A = internal bf16 qy)
// MODE 3: O0(bf16) = focus(A@B)               (A external, q-gemm; focus
//         fused: whole 256-col row is in-block; cross-wave-pair reduce)
// ---------------------------------------------------------------------------
template<int MODE>
__global__ __launch_bounds__(256, 2)
void gemm256(const void* __restrict__ Aany, const u16* __restrict__ Abf,
             const u16* __restrict__ BT, u16* __restrict__ O0,
             const void* __restrict__ extra, const int* __restrict__ flagp)
{
    const int f32 = *flagp;
    __shared__ u16 As[128 * 72];     // [m][k], stride 72
    __shared__ u16 Bs[256 * 72];     // [n][k]
    __shared__ float red2[2][128];
    __shared__ float red6[2][128];
    __shared__ float ratio_s[128];
    __shared__ float sscr[256];

    const int tid  = threadIdx.x;
    const int row0 = blockIdx.x * 128;
    const int lane = tid & 63;
    const int wv   = tid >> 6;
    const int wm   = (wv & 1) * 64;          // wave row base
    const int wn   = (wv >> 1) * 128;        // wave col base
    const int l15  = lane & 15;
    const int lq   = lane >> 4;

    if (MODE == 3) {
        const float p = ldv(extra, tid, f32);
        const float s = (p > 20.f) ? p : log1pf(expf(p));
        sscr[tid] = 1.0f / s;
    }

    const int sr = tid >> 1;              // A staging row 0..127
    const int sk = (tid & 1) * 32;        // A staging k-half

    f32x4 acc[4][8] = {};

    for (int k0 = 0; k0 < 256; k0 += 64) {
        // A: row sr, 32 u16 at k0+sk.
        u16* al = &As[sr * 72 + sk];
        const size_t arow = (size_t)(row0 + sr) * 256 + k0 + sk;
        if (MODE != 2 && f32) {
            const float* ag = (const float*)Aany + arow;
            #pragma unroll
            for (int j = 0; j < 4; ++j) {
                const float4 f0 = *reinterpret_cast<const float4*>(ag + j * 8);
                const float4 f1 = *reinterpret_cast<const float4*>(ag + j * 8 + 4);
                ushort4 p0, p1;
                p0.x = f2b(f0.x); p0.y = f2b(f0.y); p0.z = f2b(f0.z); p0.w = f2b(f0.w);
                p1.x = f2b(f1.x); p1.y = f2b(f1.y); p1.z = f2b(f1.z); p1.w = f2b(f1.w);
                *reinterpret_cast<ushort4*>(al + j * 8)     = p0;
                *reinterpret_cast<ushort4*>(al + j * 8 + 4) = p1;
            }
        } else {
            const u16* ag = ((MODE == 2) ? Abf : (const u16*)Aany) + arow;
            #pragma unroll
            for (int j = 0; j < 4; ++j)
                *reinterpret_cast<uint4*>(al + j * 8) =
                    *reinterpret_cast<const uint4*>(ag + j * 8);
        }
        // B: row tid (all 256 n), 64 u16 at k0.
        {
            u16* bl = &Bs[tid * 72];
            const u16* bg = BT + (size_t)tid * 256 + k0;
            #pragma unroll
            for (int j = 0; j < 8; ++j)
                *reinterpret_cast<uint4*>(bl + j * 8) =
                    *reinterpret_cast<const uint4*>(bg + j * 8);
        }
        __syncthreads();
        #pragma unroll
        for (int ks = 0; ks < 64; ks += 32) {
            short8 av[4], bv[8];
            #pragma unroll
            for (int i = 0; i < 4; ++i)
                av[i] = *reinterpret_cast<const short8*>(
                    &As[(wm + i * 16 + l15) * 72 + ks + lq * 8]);
            #pragma unroll
            for (int j = 0; j < 8; ++j)
                bv[j] = *reinterpret_cast<const short8*>(
                    &Bs[(wn + j * 16 + l15) * 72 + ks + lq * 8]);
            #pragma unroll
            for (int i = 0; i < 4; ++i)
                #pragma unroll
                for (int j = 0; j < 8; ++j)
                    acc[i][j] = __builtin_amdgcn_mfma_f32_16x16x32_bf16(
                        av[i], bv[j], acc[i][j], 0, 0, 0);
        }
        __syncthreads();
    }

    if (MODE == 3) {
        // focus: xv=(relu+eps)/softplus; per-row s2=sum xv^2, s6=sum xv^6.
        #pragma unroll
        for (int i = 0; i < 4; ++i) {
            #pragma unroll
            for (int rg = 0; rg < 4; ++rg) {
                const int lr = wm + i * 16 + lq * 4 + rg;   // local row 0..127
                float s2 = 0.f, s6 = 0.f;
                #pragma unroll
                for (int j = 0; j < 8; ++j) {
                    const int col = wn + j * 16 + l15;
                    const float xv =
                        (fmaxf(acc[i][j][rg], 0.f) + 1e-6f) * sscr[col];
                    acc[i][j][rg] = xv;
                    const float x2 = xv * xv;
                    s2 += x2;
                    s6 += x2 * x2 * x2;
                }
                #pragma unroll
                for (int off = 1; off < 16; off <<= 1) {
                    s2 += __shfl_xor(s2, off);
                    s6 += __shfl_xor(s6, off);
                }
                if (l15 == 0) { red2[wv >> 1][lr] = s2; red6[wv >> 1][lr] = s6; }
            }
        }
        __syncthreads();
        if (tid < 128)
            ratio_s[tid] = sqrtf((red2[0][tid] + red2[1][tid]) /
                                 (red6[0][tid] + red6[1][tid]));
        __syncthreads();
    }

    // Store. C/D layout: row=(lane>>4)*4+reg, col=lane&15 (m89-verified).
    #pragma unroll
    for (int i = 0; i < 4; ++i) {
        #pragma unroll
        for (int j = 0; j < 8; ++j) {
            const int gcol = wn + j * 16 + l15;
            #pragma unroll
            for (int rg = 0; rg < 4; ++rg) {
                const int lr = wm + i * 16 + lq * 4 + rg;
                const size_t oi = (size_t)(row0 + lr) * 256 + gcol;
                const float a = acc[i][j][rg];
                if (MODE == 0) {
                    O0[oi] = f2b(a);
                } else if (MODE == 3) {
                    O0[oi] = f2b(a * a * a * ratio_s[lr]);
                } else {
                    const float o = a + ldv(extra, gcol, f32);
                    if (f32) ((float*)O0)[oi] = o;
                    else     O0[oi] = f2b(o);
                }
            }
        }
    }
}

// ---------------------------------------------------------------------------
// Fused k-path v2: k = x @ Wkv[:, :256] + pe -> focus -> kvsum/ksum atomics.
// k never touches global memory. Grid 512; each block does TWO 64-row
// chunks, accumulating kvsum/ksum in registers (atomics once at end:
// halves atomic HBM writeback + contention).
// Phase 1 (per chunk): 64x256 GEMM (As[64][72], Bs[256][72]).
// Phase 2: +peb, focus via shfl + cross-wave LDS reduce; write K
//          TRANSPOSED into KsT[d][r] (stride 72) -> A-frag = 1 ds_read_b128.
// Phase 3: stage V tile transposed into VsT[e][r] (coalesced global read,
//          conflict-free scalar LDS transpose writes: lane=r spans all 32
//          banks evenly); kvsum = K^T V per head via MFMA, frags via b128.
// ---------------------------------------------------------------------------
__global__ __launch_bounds__(256, 2)
void fusedk_kernel(const void* __restrict__ x, const u16* __restrict__ WkvT,
                   const u16* __restrict__ peb, const u16* __restrict__ v,
                   const void* __restrict__ sp,
                   float* __restrict__ kvsm, float* __restrict__ ksm,
                   const int* __restrict__ flagp)
{
    const int f32 = *flagp;
    __shared__ u16 smem[36864];          // 73728 B, phase-aliased
    __shared__ float red2[4][64];
    __shared__ float red6[4][64];
    __shared__ float ratio_s[64];
    __shared__ float sscr[256];
    u16* As  = smem;                     // [64][72]   (GEMM)
    u16* Bs  = smem + 4608;              // [256][72]  (GEMM)
    u16* KsT = smem;                     // [256 d][72 r] (phase 2b/3)
    u16* VsT = smem + 18432;             // [256 e][72 r] (phase 3)

    const int tid  = threadIdx.x;
    const int lane = tid & 63;
    const int wv   = tid >> 6;           // 0..3
    const int l15  = lane & 15;
    const int lq   = lane >> 4;
    const int wn   = wv * 64;

    {
        const float p = ldv(sp, tid, f32);
        const float s = (p > 20.f) ? p : log1pf(expf(p));
        sscr[tid] = 1.0f / s;
    }

    f32x4 cc[2][4] = {};                 // kvsum accum (2 heads/wave)
    float ksp[4] = {0.f, 0.f, 0.f, 0.f}; // ksum accum

    const int ar = tid >> 2, ak = (tid & 3) * 16;   // A staging
    const int vr = tid & 63, veb = (tid >> 6) * 64; // V staging

    for (int c = 0; c < 2; ++c) {
        const int row0 = blockIdx.x * 128 + c * 64;
        const int nb   = row0 & 4095;

        // ---- Phase 1: GEMM ------------------------------------------------
        f32x4 acc[4][4] = {};
        for (int k0 = 0; k0 < 256; k0 += 64) {
            u16* al = &As[ar * 72 + ak];
            const size_t arow = (size_t)(row0 + ar) * 256 + k0 + ak;
            if (f32) {
                const float* ag = (const float*)x + arow;
                #pragma unroll
                for (int j = 0; j < 2; ++j) {
                    const float4 f0 = *reinterpret_cast<const float4*>(ag + j * 8);
                    const float4 f1 = *reinterpret_cast<const float4*>(ag + j * 8 + 4);
                    ushort4 p0, p1;
                    p0.x = f2b(f0.x); p0.y = f2b(f0.y); p0.z = f2b(f0.z); p0.w = f2b(f0.w);
                    p1.x = f2b(f1.x); p1.y = f2b(f1.y); p1.z = f2b(f1.z); p1.w = f2b(f1.w);
                    *reinterpret_cast<ushort4*>(al + j * 8)     = p0;
                    *reinterpret_cast<ushort4*>(al + j * 8 + 4) = p1;
                }
            } else {
                const u16* ag = (const u16*)x + arow;
                #pragma unroll
                for (int j = 0; j < 2; ++j)
                    *reinterpret_cast<uint4*>(al + j * 8) =
                        *reinterpret_cast<const uint4*>(ag + j * 8);
            }
            {
                u16* bl = &Bs[tid * 72];
                const u16* bg = WkvT + (size_t)tid * 256 + k0;
                #pragma unroll
                for (int j = 0; j < 8; ++j)
                    *reinterpret_cast<uint4*>(bl + j * 8) =
                        *reinterpret_cast<const uint4*>(bg + j * 8);
            }
            __syncthreads();
            #pragma unroll
            for (int ks = 0; ks < 64; ks += 32) {
                short8 av[4], bvv[4];
                #pragma unroll
                for (int i = 0; i < 4; ++i)
                    av[i] = *reinterpret_cast<const short8*>(
                        &As[(i * 16 + l15) * 72 + ks + lq * 8]);
                #pragma unroll
                for (int j = 0; j < 4; ++j)
                    bvv[j] = *reinterpret_cast<const short8*>(
                        &Bs[(wn + j * 16 + l15) * 72 + ks + lq * 8]);
                #pragma unroll
                for (int i = 0; i < 4; ++i)
                    #pragma unroll
                    for (int j = 0; j < 4; ++j)
                        acc[i][j] = __builtin_amdgcn_mfma_f32_16x16x32_bf16(
                            av[i], bvv[j], acc[i][j], 0, 0, 0);
            }
            __syncthreads();
        }

        // ---- Phase 2a: +peb, normalize, s2/s6 reduce ----------------------
        #pragma unroll
        for (int i = 0; i < 4; ++i) {
            #pragma unroll
            for (int rg = 0; rg < 4; ++rg) {
                const int lrow = i * 16 + lq * 4 + rg;
                float s2 = 0.f, s6 = 0.f;
                #pragma unroll
                for (int j = 0; j < 4; ++j) {
                    const int col = wn + j * 16 + l15;
                    const float t = acc[i][j][rg] +
                        b2f(peb[(size_t)(nb + lrow) * 256 + col]);
                    const float xv = (fmaxf(t, 0.f) + 1e-6f) * sscr[col];
                    acc[i][j][rg] = xv;
                    const float x2 = xv * xv;
                    s2 += x2;
                    s6 += x2 * x2 * x2;
                }
                #pragma unroll
                for (int off = 1; off < 16; off <<= 1) {
                    s2 += __shfl_xor(s2, off);
                    s6 += __shfl_xor(s6, off);
                }
                if (l15 == 0) { red2[wv][lrow] = s2; red6[wv][lrow] = s6; }
            }
        }
        __syncthreads();
        if (tid < 64) {
            const float s2t = red2[0][tid] + red2[1][tid] + red2[2][tid] + red2[3][tid];
            const float s6t = red6[0][tid] + red6[1][tid] + red6[2][tid] + red6[3][tid];
            ratio_s[tid] = sqrtf(s2t / s6t);
        }
        __syncthreads();

        // ---- Phase 2b: finalize k -> KsT[d][r]; ksum partials. ------------
        {
            float kscol[4] = {0.f, 0.f, 0.f, 0.f};
            #pragma unroll
            for (int i = 0; i < 4; ++i) {
                #pragma unroll
                for (int rg = 0; rg < 4; ++rg) {
                    const int lrow = i * 16 + lq * 4 + rg;
                    const float rt = ratio_s[lrow];
                    #pragma unroll
                    for (int j = 0; j < 4; ++j) {
                        const float xv = acc[i][j][rg];
                        const float kf = xv * xv * xv * rt;
                        KsT[(wn + j * 16 + l15) * 72 + lrow] = f2b(kf);
                        kscol[j] += kf;
                    }
                }
            }
            #pragma unroll
            for (int j = 0; j < 4; ++j) {
                float kp = kscol[j];
                kp += __shfl_xor(kp, 16);
                kp += __shfl_xor(kp, 32);
                ksp[j] += kp;
            }
        }

        // ---- Stage V transposed: VsT[e][r]. Writes conflict-free. ---------
        {
            const u16* vg = v + (size_t)(row0 + vr) * 256 + veb;
            uint4 t0[8];
            #pragma unroll
            for (int j = 0; j < 8; ++j)
                t0[j] = *reinterpret_cast<const uint4*>(vg + j * 8);
            #pragma unroll
            for (int j = 0; j < 8; ++j) {
                const u16* pp = (const u16*)&t0[j];
                #pragma unroll
                for (int m = 0; m < 8; ++m)
                    VsT[(veb + j * 8 + m) * 72 + vr] = pp[m];
            }
        }
        __syncthreads();

        // ---- Phase 3: kvsum += K^T V per head via MFMA (b128 frags). ------
        #pragma unroll
        for (int hh = 0; hh < 2; ++hh) {
            const int cb = (wv * 2 + hh) * 32;
            #pragma unroll
            for (int kk = 0; kk < 64; kk += 32) {
                const short8 a0 = *reinterpret_cast<const short8*>(
                    &KsT[(cb + l15) * 72 + kk + lq * 8]);
                const short8 a1 = *reinterpret_cast<const short8*>(
                    &KsT[(cb + 16 + l15) * 72 + kk + lq * 8]);
                const short8 b0 = *reinterpret_cast<const short8*>(
                    &VsT[(cb + l15) * 72 + kk + lq * 8]);
                const short8 b1 = *reinterpret_cast<const short8*>(
                    &VsT[(cb + 16 + l15) * 72 + kk + lq * 8]);
                cc[hh][0] = __builtin_amdgcn_mfma_f32_16x16x32_bf16(a0, b0, cc[hh][0], 0, 0, 0);
                cc[hh][1] = __builtin_amdgcn_mfma_f32_16x16x32_bf16(a0, b1, cc[hh][1], 0, 0, 0);
                cc[hh][2] = __builtin_amdgcn_mfma_f32_16x16x32_bf16(a1, b0, cc[hh][2], 0, 0, 0);
                cc[hh][3] = __builtin_amdgcn_mfma_f32_16x16x32_bf16(a1, b1, cc[hh][3], 0, 0, 0);
            }
        }
        __syncthreads();
    }

    // ---- Atomics once per block. -----------------------------------------
    const int b = (blockIdx.x * 128) >> 12;
    #pragma unroll
    for (int j = 0; j < 4; ++j)
        if (lane < 16)
            atomicAdd(&ksm[(size_t)b * 256 + wn + j * 16 + lane], ksp[j]);
    #pragma unroll
    for (int hh = 0; hh < 2; ++hh) {
        const int h = wv * 2 + hh;
        float* base = kvsm + (size_t)(b * 8 + h) * 1024;
        #pragma unroll
        for (int rg = 0; rg < 4; ++rg) {
            const int d0 = lq * 4 + rg;
            atomicAdd(&base[(size_t)d0 * 32 + l15],             cc[hh][0][rg]);
            atomicAdd(&base[(size_t)d0 * 32 + 16 + l15],        cc[hh][1][rg]);
            atomicAdd(&base[(size_t)(d0 + 16) * 32 + l15],      cc[hh][2][rg]);
            atomicAdd(&base[(size_t)(d0 + 16) * 32 + 16 + l15], cc[hh][3][rg]);
        }
    }
}

// ---------------------------------------------------------------------------
// attn IN-PLACE on qy.
// ---------------------------------------------------------------------------
__global__ __launch_bounds__(256)
void attn_kernel(u16* qy, const float* __restrict__ kvsum,
                 const float* __restrict__ ksum)
{
    __shared__ float kvs[8][32][32];
    __shared__ float km[8][32];
    __shared__ float qs[16][256];
    const int tid = threadIdx.x;
    const int b   = blockIdx.x >> 8;
    const int n0  = (blockIdx.x & 255) * 16;
    const float inv_n = 1.0f / 4096.0f;
    for (int i = tid; i < 8 * 32 * 32; i += 256)
        (&kvs[0][0][0])[i] = kvsum[(size_t)b * 8192 + i] * inv_n;
    (&km[0][0])[tid] = ksum[(size_t)b * 256 + tid] * inv_n;
    u16* qb = qy + ((size_t)b * 4096 + n0) * 256;
    #pragma unroll
    for (int t = 0; t < 16; ++t)
        qs[t][tid] = b2f(qb[(size_t)t * 256 + tid]);
    __syncthreads();
    const int h = tid >> 5, e = tid & 31;
    for (int t = 0; t < 16; ++t) {
        float acc = 0.f, zd = 0.f;
        #pragma unroll
        for (int d = 0; d < 32; ++d) {
            const float qv = qs[t][h * 32 + d];
            acc = fmaf(qv, kvs[h][d][e], acc);
            zd  = fmaf(qv, km[h][d], zd);
        }
        qb[(size_t)t * 256 + tid] = f2b(acc / (zd + 1e-6f));
    }
}

// ---------------------------------------------------------------------------
// Depthwise 5x5 conv: LDS-staged 12x12x256 halo tile (vectorized uint4
// staging), thread=channel, register-resident sliding 5x12 window, 8x8
// outputs/thread, += into y with bias.
// ---------------------------------------------------------------------------
__global__ __launch_bounds__(256, 2)
void conv_add_kernel(const u16* __restrict__ v, const void* __restrict__ w,
                     const void* __restrict__ bias, u16* __restrict__ y,
                     const int* __restrict__ flagp)
{
    const int f32 = *flagp;
    __shared__ u16 vt[144 * 256];   // [py*12+px][ch], 73728 B
    __shared__ float wl[800];
    __shared__ float bl[32];
    const int tid = threadIdx.x;
    for (int i = tid; i < 800; i += 256) wl[i] = ldv(w, i, f32);
    if (tid < 32) bl[tid] = ldv(bias, tid, f32);

    const int bb = blockIdx.x >> 6;
    const int ty = (blockIdx.x >> 3) & 7;
    const int tx = blockIdx.x & 7;
    const int y0 = ty * 8, x0 = tx * 8;
    const u16* vb = v + (size_t)bb * 4096 * 256;

    #pragma unroll
    for (int it = 0; it < 18; ++it) {
        const int idx = it * 256 + tid;       // 0..4607
        const int px  = idx >> 5;             // 0..143
        const int c8  = (idx & 31) * 8;
        const int py  = px / 12, pxx = px - py * 12;
        const int yy = y0 + py - 2, xx = x0 + pxx - 2;
        uint4 val = {0u, 0u, 0u, 0u};
        if (yy >= 0 && yy < 64 && xx >= 0 && xx < 64)
            val = *reinterpret_cast<const uint4*>(
                vb + (size_t)((yy << 6) + xx) * 256 + c8);
        *reinterpret_cast<uint4*>(&vt[px * 256 + c8]) = val;
    }
    __syncthreads();

    const int c  = tid;            // channel
    const int dc = c & 31;
    float wreg[25];
    #pragma unroll
    for (int i = 0; i < 25; ++i) wreg[i] = wl[dc * 25 + i];
    const float bv = bl[dc];

    float win[5][12];
    #pragma unroll
    for (int r = 0; r < 5; ++r)
        #pragma unroll
        for (int cc = 0; cc < 12; ++cc)
            win[r][cc] = b2f(vt[(r * 12 + cc) * 256 + c]);

    u16* yb = y + ((size_t)bb * 4096 + (size_t)y0 * 64 + x0) * 256 + c;
    #pragma unroll
    for (int oy = 0; oy < 8; ++oy) {
        if (oy) {
            #pragma unroll
            for (int r = 0; r < 4; ++r)
                #pragma unroll
                for (int cc = 0; cc < 12; ++cc) win[r][cc] = win[r + 1][cc];
            #pragma unroll
            for (int cc = 0; cc < 12; ++cc)
                win[4][cc] = b2f(vt[((oy + 4) * 12 + cc) * 256 + c]);
        }
        #pragma unroll
        for (int ox = 0; ox < 8; ++ox) {
            float s = 0.f;
            #pragma unroll
            for (int ky = 0; ky < 5; ++ky)
                #pragma unroll
                for (int kx = 0; kx < 5; ++kx)
                    s = fmaf(win[ky][ox + kx], wreg[ky * 5 + kx], s);
            u16* yp = yb + (size_t)(oy * 64 + ox) * 256;
            *yp = f2b(b2f(*yp) + s + bv);
        }
    }
}

// ---------------------------------------------------------------------------
extern "C" void kernel_launch(void* const* d_in, const int* in_sizes, int n_in,
                              void* d_out, int out_size, void* d_ws, size_t ws_size,
                              hipStream_t stream)
{
    (void)in_sizes; (void)n_in; (void)out_size; (void)ws_size;
    const void* x   = d_in[0];
    const void* Wq  = d_in[1];
    const void* Wkv = d_in[2];
    const void* Wp  = d_in[3];
    const void* bp  = d_in[4];
    const void* sp  = d_in[5];
    const void* pe  = d_in[6];
    const void* dw  = d_in[7];
    const void* db  = d_in[8];

    // ws layout (~36 MB):
    // [flag 64B][kvsm 512K][ksm 16K][WqT 128K][WkvT 256K][WpT 128K][peb 2M][qy 33.5M]
    int*   flag = (int*)d_ws;
    float* kvsm = (float*)((char*)d_ws + 64);
    float* ksm  = kvsm + 131072;
    u16*   WqT  = (u16*)(ksm + 4096);
    u16*   WkvT = WqT + 65536;
    u16*   WpT  = WkvT + 131072;
    u16*   peb  = WpT + 65536;
    u16*   qy   = peb + 1048576;
    // v (bf16, 33.5 MB) parked at the START of d_out (dead before the final
    // GEMM overwrites d_out).
    u16*   v    = (u16*)d_out;

    hipMemsetAsync(kvsm, 0, (131072 + 4096) * sizeof(float), stream);
    detect_kernel<<<1, 64, 0, stream>>>(x, flag);
    pecvt_kernel<<<1024, 256, 0, stream>>>(pe, peb, flag);
    wtrans_kernel<<<64, 256, 0, stream>>>(Wq, WqT, 256, flag);
    wtrans_kernel<<<128, 256, 0, stream>>>(Wkv, WkvT, 512, flag);
    wtrans_kernel<<<64, 256, 0, stream>>>(Wp, WpT, 256, flag);

    // q = focus(x @ Wq)  (focus fused into epilogue)
    hipLaunchKernelGGL((gemm256<3>), dim3(512), dim3(256), 0, stream,
                       x, (const u16*)nullptr, WqT, qy, sp, flag);
    // v = x @ Wkv[:, 256:]  (WkvT rows 256..511)
    hipLaunchKernelGGL((gemm256<0>), dim3(512), dim3(256), 0, stream,
                       x, (const u16*)nullptr, WkvT + (size_t)256 * 256, v,
                       (const void*)nullptr, flag);
    // fused k path: gemm + pe + focus + kvsum/ksum (k never materialized)
    fusedk_kernel<<<512, 256, 0, stream>>>(x, WkvT, peb, v, sp, kvsm, ksm, flag);

    attn_kernel<<<4096, 256, 0, stream>>>(qy, kvsm, ksm);
    conv_add_kernel<<<1024, 256, 0, stream>>>(v, dw, db, qy, flag);
    hipLaunchKernelGGL((gemm256<2>), dim3(512), dim3(256), 0, stream,
                       (const void*)nullptr, qy, WpT, (u16*)d_out, bp, flag);
}